// Round 12
// baseline (271.267 us; speedup 1.0000x reference)
//
#include <hip/hip_runtime.h>
#include <hip/hip_bf16.h>

#define BB 8
#define SS 2048
#define DD 384
#define HH 8
#define HD 48
#define QT 32
#define KT 64

typedef unsigned short u16;
typedef unsigned int u32;
typedef unsigned short u16x4 __attribute__((ext_vector_type(4)));
typedef unsigned short u16x8 __attribute__((ext_vector_type(8)));
typedef unsigned int u32x2 __attribute__((ext_vector_type(2)));
typedef short s16x8 __attribute__((ext_vector_type(8)));
typedef float f32x4 __attribute__((ext_vector_type(4)));

__device__ __forceinline__ float bf2f(u16 v){
  union { u32 u; float f; } x; x.u = ((u32)v) << 16; return x.f;
}
__device__ __forceinline__ u16 f2bf(float f){
  union { float f; u32 u; } x; x.f = f;
  u32 r = x.u + 0x7fffu + ((x.u >> 16) & 1u);
  return (u16)(r >> 16);
}
// split fp32 into hi (truncated bf16) + lo (bf16 of residual); hi+lo ~ 17-bit mantissa
__device__ __forceinline__ void split2(float f, u16& h, u16& l){
  union { float f; u32 u; } x; x.f = f;
  h = (u16)(x.u >> 16);
  l = f2bf(f - bf2f(h));
}
// pack two f32 -> two truncated bf16 in one u32 (lo = a, hi = b)
__device__ __forceinline__ u32 pack_trunc2(float a, float b){
  union { float f; u32 u; } xa, xb; xa.f = a; xb.f = b;
  return (xa.u >> 16) | (xb.u & 0xffff0000u);
}

// lgkm-only barrier: LDS writes visible, but global loads stay in flight
#define LBAR() do { \
  asm volatile("s_waitcnt lgkmcnt(0)" ::: "memory"); \
  __builtin_amdgcn_s_barrier(); \
  asm volatile("" ::: "memory"); \
} while (0)

// ---------------- Kernel 1: QKV projection, split-bf16 MFMA GEMM ----------------
// (round-6 proven version) C = x * Wqkv^T ; scatter to Q (pre-scaled by
// log2(e)/sqrt(48)), K ([B,H,S,48]) and V^T ([B,H,48,S]) bf16 with bias.
__global__ __launch_bounds__(512, 4) void qkv_gemm(
    const float* __restrict__ x, const float* __restrict__ W,
    const float* __restrict__ bias,
    u16* __restrict__ Q, u16* __restrict__ Kd, u16* __restrict__ Vt)
{
  __shared__ u16 Ah[128][40], Al[128][40], Bh[128][40], Bl[128][40];
  const int tid  = threadIdx.x;
  const int w    = tid >> 6, lane = tid & 63;
  const int lg   = lane >> 4, ln = lane & 15;
  const int wm   = w >> 1, wn = w & 1;
  const int mb   = blockIdx.x / 9, nb = blockIdx.x % 9;
  const int m0   = mb * 128, n0 = nb * 128;
  const int srow = tid >> 3, sk4 = (tid & 7) << 2;
  const float qscale = 0.2082350972f;  // log2(e)/sqrt(48)

  f32x4 acc[8];
  #pragma unroll
  for (int i = 0; i < 8; i++) acc[i] = (f32x4){0.f,0.f,0.f,0.f};

  for (int ks = 0; ks < 12; ks++){
    const int k0 = ks * 32;
    __syncthreads();
    #pragma unroll
    for (int p = 0; p < 2; p++){
      const int row = srow + p*64;
      float4 av = *(const float4*)(x + (long)(m0+row)*DD + k0 + sk4);
      float4 bv = *(const float4*)(W + (long)(n0+row)*DD + k0 + sk4);
      u16 h0,l0,h1,l1,h2,l2,h3,l3;
      split2(av.x,h0,l0); split2(av.y,h1,l1); split2(av.z,h2,l2); split2(av.w,h3,l3);
      *(u16x4*)&Ah[row][sk4] = (u16x4){h0,h1,h2,h3};
      *(u16x4*)&Al[row][sk4] = (u16x4){l0,l1,l2,l3};
      split2(bv.x,h0,l0); split2(bv.y,h1,l1); split2(bv.z,h2,l2); split2(bv.w,h3,l3);
      *(u16x4*)&Bh[row][sk4] = (u16x4){h0,h1,h2,h3};
      *(u16x4*)&Bl[row][sk4] = (u16x4){l0,l1,l2,l3};
    }
    __syncthreads();
    s16x8 bh[4], bl[4];
    #pragma unroll
    for (int fn = 0; fn < 4; fn++){
      const int br = wn*64 + fn*16 + ln;
      bh[fn] = *(const s16x8*)&Bh[br][lg*8];
      bl[fn] = *(const s16x8*)&Bl[br][lg*8];
    }
    #pragma unroll
    for (int fm = 0; fm < 2; fm++){
      const int ar = wm*32 + fm*16 + ln;
      s16x8 ah = *(const s16x8*)&Ah[ar][lg*8];
      s16x8 al = *(const s16x8*)&Al[ar][lg*8];
      #pragma unroll
      for (int fn = 0; fn < 4; fn++){
        f32x4 c = acc[fm*4+fn];
        c = __builtin_amdgcn_mfma_f32_16x16x32_bf16(ah, bh[fn], c, 0, 0, 0);
        c = __builtin_amdgcn_mfma_f32_16x16x32_bf16(ah, bl[fn], c, 0, 0, 0);
        c = __builtin_amdgcn_mfma_f32_16x16x32_bf16(al, bh[fn], c, 0, 0, 0);
        acc[fm*4+fn] = c;
      }
    }
  }
  #pragma unroll
  for (int fm = 0; fm < 2; fm++){
    #pragma unroll
    for (int fn = 0; fn < 4; fn++){
      const int e = n0 + wn*64 + fn*16 + ln;
      const float bi = bias[e];
      const int h = e / 144, c = e % 144;
      #pragma unroll
      for (int r = 0; r < 4; r++){
        const int mm = m0 + wm*32 + fm*16 + lg*4 + r;
        const int bb = mm >> 11, s = mm & 2047;
        const float v = acc[fm*4+fn][r] + bi;
        if (c < 48)       Q[(((long)(bb*HH + h))*SS + s)*HD + c] = f2bf(v * qscale);
        else if (c < 96)  Kd[(((long)(bb*HH + h))*SS + s)*HD + (c-48)] = f2bf(v);
        else              Vt[(((long)(bb*HH + h))*HD + (c-96))*SS + s] = f2bf(v);
      }
    }
  }
}

// ---------------- Kernel 2: MFMA attention, in-register head-softmax ----------------
// Block: one (b, 32-query tile), 8 waves, 64 keys/iter, ONE barrier/iter.
// Wave roles: for QK^T, wave w = (qs = w>>2, ksl = w&3) computes ALL 8 heads
// for its 16-key slice -> each lane holds the 8 head-scores for its (q,k)
// pairs in registers -> softmax is pure register math (no LDS, no latency).
// P goes to double-buffered LDS (Pb[2]); for PV, wave w = head w consumes
// all 64 keys. WAR on Pb[cb] is separated by >=1 barrier (write t+2 vs read t).
__global__ __launch_bounds__(512, 2) void attn_kernel(
    const u16* __restrict__ Q, const u16* __restrict__ K,
    const u16* __restrict__ Vg, float* __restrict__ vals)
{
  __shared__ u16 Pb[2][HH][QT][72];   // bf16 P [cb][h][q][64k+pad], 144B rows

  const int tid  = threadIdx.x;
  const int w    = tid >> 6;
  const int lane = tid & 63;
  const int lg   = lane >> 4;
  const int ln   = lane & 15;
  const int qs   = w >> 2;        // QK^T role: q-subtile (0..1)
  const int ksl  = w & 3;         // QK^T role: 16-key slice (0..3)
  const int h    = w;             // PV role: head

  // XCD-chunked swizzle: 512 blocks, 8 XCDs -> XCD x gets exactly batch b=x.
  const int wg = ((int)blockIdx.x % 8) * 64 + (int)blockIdx.x / 8;
  const int b  = wg >> 6;
  const int qt = wg & 63;
  const int q0 = qt * QT;

  const long bh0   = (long)(b*HH);
  const long hbase = (bh0 + h) * SS;
  const u16* vbase = Vg + (bh0 + h) * HD * SS;
  const s16x8 z8 = (s16x8){0,0,0,0,0,0,0,0};

  // Q fragments (B operand of swapped QK^T) for ALL 8 heads, own q-subtile.
  s16x8 qfA[8], qfB[8];
  #pragma unroll
  for (int h2 = 0; h2 < 8; h2++){
    const u16* qp = Q + ((bh0 + h2)*SS + q0 + qs*16 + ln)*HD;
    qfA[h2] = *(const s16x8*)(qp + lg*8);
    if (lane < 32) qfB[h2] = *(const s16x8*)(qp + 32 + lg*8);
    else           qfB[h2] = z8;
  }

  f32x4 oacc[2][3];
  #pragma unroll
  for (int q2 = 0; q2 < 2; q2++)
    #pragma unroll
    for (int c = 0; c < 3; c++) oacc[q2][c] = (f32x4){0.f,0.f,0.f,0.f};

  int cb = 0;
  for (int t = 0; t < SS/KT; t++){
    const int k0 = t * KT;
    const int kk = k0 + ksl*16;

    // --- K fragments: all 8 heads for this wave's 16-key slice ---
    s16x8 kA[8], kB[8];
    #pragma unroll
    for (int h2 = 0; h2 < 8; h2++){
      const u16* kp = K + ((bh0 + h2)*SS + kk + ln)*HD;
      kA[h2] = *(const s16x8*)(kp + lg*8);
      if (lane < 32) kB[h2] = *(const s16x8*)(kp + 32 + lg*8);
      else           kB[h2] = z8;
    }

    // --- QK^T (swapped): sc[h2] = S[h2][q=q0+qs*16+ln][k=kk+lg*4+r] ---
    f32x4 sc[8];
    __builtin_amdgcn_s_setprio(1);
    #pragma unroll
    for (int h2 = 0; h2 < 8; h2++){
      f32x4 a = (f32x4){0.f,0.f,0.f,0.f};
      a = __builtin_amdgcn_mfma_f32_16x16x32_bf16(kA[h2], qfA[h2], a, 0, 0, 0);
      a = __builtin_amdgcn_mfma_f32_16x16x32_bf16(kB[h2], qfB[h2], a, 0, 0, 0);
      sc[h2] = a;
    }
    __builtin_amdgcn_s_setprio(0);

    // --- V fragments (PV role): issued here, consumed after the barrier ---
    s16x8 vf[3][2];
    #pragma unroll
    for (int c = 0; c < 3; c++)
      #pragma unroll
      for (int ks2 = 0; ks2 < 2; ks2++)
        vf[c][ks2] = *(const s16x8*)(vbase + (long)(c*16 + ln)*SS + k0 + ks2*32 + lg*8);

    // --- in-register softmax over the 8 heads (per owned (q,k)) ---
    #pragma unroll
    for (int r = 0; r < 4; r++){
      float e0 = __builtin_amdgcn_exp2f(sc[0][r]);
      float e1 = __builtin_amdgcn_exp2f(sc[1][r]);
      float e2 = __builtin_amdgcn_exp2f(sc[2][r]);
      float e3 = __builtin_amdgcn_exp2f(sc[3][r]);
      float e4 = __builtin_amdgcn_exp2f(sc[4][r]);
      float e5 = __builtin_amdgcn_exp2f(sc[5][r]);
      float e6 = __builtin_amdgcn_exp2f(sc[6][r]);
      float e7 = __builtin_amdgcn_exp2f(sc[7][r]);
      float rs = __builtin_amdgcn_rcpf(((e0+e1)+(e2+e3))+((e4+e5)+(e6+e7)));
      sc[0][r] = e0*rs; sc[1][r] = e1*rs; sc[2][r] = e2*rs; sc[3][r] = e3*rs;
      sc[4][r] = e4*rs; sc[5][r] = e5*rs; sc[6][r] = e6*rs; sc[7][r] = e7*rs;
    }

    // --- P to LDS: 8 x ds_write_b64 (packed bf16 quads) ---
    #pragma unroll
    for (int h2 = 0; h2 < 8; h2++){
      u32x2 pw;
      pw[0] = pack_trunc2(sc[h2][0], sc[h2][1]);
      pw[1] = pack_trunc2(sc[h2][2], sc[h2][3]);
      *(u32x2*)&Pb[cb][h2][qs*16 + ln][ksl*16 + lg*4] = pw;
    }
    LBAR();   // Pb[cb] visible; >=1 barrier separates reads(t) from writes(t+2)

    // --- PV (head role): O[32q][48d] += P[32q][64k] * V[64k][48d] ---
    __builtin_amdgcn_s_setprio(1);
    #pragma unroll
    for (int q2 = 0; q2 < 2; q2++){
      #pragma unroll
      for (int ks2 = 0; ks2 < 2; ks2++){
        s16x8 pf = *(const s16x8*)&Pb[cb][h][q2*16 + ln][ks2*32 + lg*8];
        oacc[q2][0] = __builtin_amdgcn_mfma_f32_16x16x32_bf16(pf, vf[0][ks2], oacc[q2][0], 0, 0, 0);
        oacc[q2][1] = __builtin_amdgcn_mfma_f32_16x16x32_bf16(pf, vf[1][ks2], oacc[q2][1], 0, 0, 0);
        oacc[q2][2] = __builtin_amdgcn_mfma_f32_16x16x32_bf16(pf, vf[2][ks2], oacc[q2][2], 0, 0, 0);
      }
    }
    __builtin_amdgcn_s_setprio(0);
    cb ^= 1;
  }

  // store vals[b][h][q][d] fp32 (bug-compatible flat layout)
  float* op = vals + (hbase + q0)*HD;
  #pragma unroll
  for (int q2 = 0; q2 < 2; q2++)
    #pragma unroll
    for (int c = 0; c < 3; c++)
      #pragma unroll
      for (int r = 0; r < 4; r++)
        op[(long)(q2*16 + lg*4 + r)*HD + c*16 + ln] = oacc[q2][c][r];
}

// ---------------- Kernel 3: output projection, split-bf16 MFMA GEMM ----------------
// (round-6 proven version)
__global__ __launch_bounds__(512, 4) void out_gemm(
    const float* __restrict__ A, const float* __restrict__ W,
    const float* __restrict__ bias, float* __restrict__ out)
{
  __shared__ u16 Ah[128][40], Al[128][40], Bh[128][40], Bl[128][40];
  const int tid  = threadIdx.x;
  const int w    = tid >> 6, lane = tid & 63;
  const int lg   = lane >> 4, ln = lane & 15;
  const int wm   = w >> 1, wn = w & 1;
  const int mb   = blockIdx.x / 3, nb = blockIdx.x % 3;
  const int m0   = mb * 128, n0 = nb * 128;
  const int srow = tid >> 3, sk4 = (tid & 7) << 2;

  f32x4 acc[8];
  #pragma unroll
  for (int i = 0; i < 8; i++) acc[i] = (f32x4){0.f,0.f,0.f,0.f};

  for (int ks = 0; ks < 12; ks++){
    const int k0 = ks * 32;
    __syncthreads();
    #pragma unroll
    for (int p = 0; p < 2; p++){
      const int row = srow + p*64;
      float4 av = *(const float4*)(A + (long)(m0+row)*DD + k0 + sk4);
      float4 bv = *(const float4*)(W + (long)(n0+row)*DD + k0 + sk4);
      u16 h0,l0,h1,l1,h2,l2,h3,l3;
      split2(av.x,h0,l0); split2(av.y,h1,l1); split2(av.z,h2,l2); split2(av.w,h3,l3);
      *(u16x4*)&Ah[row][sk4] = (u16x4){h0,h1,h2,h3};
      *(u16x4*)&Al[row][sk4] = (u16x4){l0,l1,l2,l3};
      split2(bv.x,h0,l0); split2(bv.y,h1,l1); split2(bv.z,h2,l2); split2(bv.w,h3,l3);
      *(u16x4*)&Bh[row][sk4] = (u16x4){h0,h1,h2,h3};
      *(u16x4*)&Bl[row][sk4] = (u16x4){l0,l1,l2,l3};
    }
    __syncthreads();
    s16x8 bh[4], bl[4];
    #pragma unroll
    for (int fn = 0; fn < 4; fn++){
      const int br = wn*64 + fn*16 + ln;
      bh[fn] = *(const s16x8*)&Bh[br][lg*8];
      bl[fn] = *(const s16x8*)&Bl[br][lg*8];
    }
    #pragma unroll
    for (int fm = 0; fm < 2; fm++){
      const int ar = wm*32 + fm*16 + ln;
      s16x8 ah = *(const s16x8*)&Ah[ar][lg*8];
      s16x8 al = *(const s16x8*)&Al[ar][lg*8];
      #pragma unroll
      for (int fn = 0; fn < 4; fn++){
        f32x4 c = acc[fm*4+fn];
        c = __builtin_amdgcn_mfma_f32_16x16x32_bf16(ah, bh[fn], c, 0, 0, 0);
        c = __builtin_amdgcn_mfma_f32_16x16x32_bf16(ah, bl[fn], c, 0, 0, 0);
        c = __builtin_amdgcn_mfma_f32_16x16x32_bf16(al, bh[fn], c, 0, 0, 0);
        acc[fm*4+fn] = c;
      }
    }
  }
  #pragma unroll
  for (int fm = 0; fm < 2; fm++){
    #pragma unroll
    for (int fn = 0; fn < 4; fn++){
      const int e = n0 + wn*64 + fn*16 + ln;
      const float bi = bias[e];
      #pragma unroll
      for (int r = 0; r < 4; r++){
        const int mm = m0 + wm*32 + fm*16 + lg*4 + r;
        out[(long)mm*DD + e] = acc[fm*4+fn][r] + bi;
      }
    }
  }
}

extern "C" void kernel_launch(void* const* d_in, const int* in_sizes, int n_in,
                              void* d_out, int out_size, void* d_ws, size_t ws_size,
                              hipStream_t stream)
{
  const float* x    = (const float*)d_in[0];
  const float* Wqkv = (const float*)d_in[1];
  const float* bqkv = (const float*)d_in[2];
  const float* Wo   = (const float*)d_in[3];
  const float* bo   = (const float*)d_in[4];
  float* out = (float*)d_out;

  const size_t QSZ = (size_t)BB*HH*SS*HD;   // 6,291,456 elems
  u16* Q  = (u16*)d_ws;
  u16* K  = Q + QSZ;
  u16* Vt = K + QSZ;                        // V^T [B,H,48,S]
  float* vals = (float*)(Vt + QSZ);         // fp32, 25.2 MB

  qkv_gemm<<<1152, 512, 0, stream>>>(x, Wqkv, bqkv, Q, K, Vt);
  attn_kernel<<<512, 512, 0, stream>>>(Q, K, Vt, vals);
  out_gemm<<<384, 512, 0, stream>>>(vals, Wo, bo, out);
}